// Round 9
// baseline (158.466 us; speedup 1.0000x reference)
//
#include <hip/hip_runtime.h>
#include <hip/hip_fp16.h>
#include <math.h>

#define N_NODES 50000
#define N_EDGES 800000
#define D 128
#define BN_EPS 1e-5f
#define N_TILES 3125   // 50000 / 16
#define CAP 64         // max degree capacity (Poisson(16); P(deg>64) ~ 1e-19)
#define SPMM_BLOCKS 2048
#define SCOLS 32       // columns per XCD-pinned slice (3.2 MB fp16 -> fits 4 MiB L2)
#define RROWS 6250     // N_NODES / 8: rows per XCD group
#define QCAP 106496    // queue capacity per group (mean 100k, sigma ~300)

typedef __attribute__((ext_vector_type(8))) _Float16 half8;
typedef __attribute__((ext_vector_type(4))) float floatx4;

// ---------------- octonion Hamilton tables ----------------
__device__ __constant__ int OCT_C[8][8] = {
    {0,1,2,3,4,5,6,7},
    {1,0,3,2,5,4,7,6},
    {2,3,0,1,6,7,4,5},
    {3,2,1,0,7,6,5,4},
    {4,5,6,7,0,1,2,3},
    {5,4,7,6,1,0,3,2},
    {6,7,4,5,2,3,0,1},
    {7,6,5,4,3,2,1,0}};
__device__ __constant__ float OCT_S[8][8] = {
    { 1,-1,-1,-1,-1,-1,-1,-1},
    { 1, 1,-1, 1,-1, 1, 1,-1},
    { 1, 1, 1,-1,-1,-1, 1, 1},
    { 1,-1, 1, 1,-1, 1,-1, 1},
    { 1, 1, 1, 1, 1,-1,-1,-1},
    { 1,-1, 1,-1, 1, 1, 1,-1},
    { 1,-1,-1, 1, 1,-1, 1, 1},
    { 1, 1,-1,-1, 1, 1,-1, 1}};

// ---------------- setup: build Ht + zero cnt/stats/qtail ----------------
__global__ void setup_kernel(const float* __restrict__ W, __half* __restrict__ Ht,
                             int* __restrict__ cnt, float* __restrict__ stats,
                             int* __restrict__ qtail) {
    int i = blockIdx.x * 256 + threadIdx.x;
    if (i < D * D) {
        int ccol = i >> 7, k = i & 127;
        int ii = k >> 4, kw = k & 15, j = ccol >> 4, m = ccol & 15;
        Ht[i] = __float2half(OCT_S[j][ii] * W[kw * D + OCT_C[j][ii] * 16 + m]);
    }
    if (i < N_NODES) cnt[i] = 0;
    if (i < 2 * D) stats[i] = 0.0f;
    if (i < 8) qtail[i] = 0;
}

// ---------------- phase A: bin edges into 8 per-XCD-group queues ----------------
// grid 3125 x 256 == N_EDGES exactly; block-LDS aggregation -> 8 global atomics/block
__global__ __launch_bounds__(256) void bin_kernel(const int* __restrict__ arow,
                                                  const int* __restrict__ acol,
                                                  const float* __restrict__ aval,
                                                  int* __restrict__ qtail,
                                                  uint2* __restrict__ qdata) {
    __shared__ int lcnt[8], lbase[8];
    const int tid = threadIdx.x;
    const int i = blockIdx.x * 256 + tid;
    if (tid < 8) lcnt[tid] = 0;
    __syncthreads();
    int r = arow[i];
    int g = r / RROWS;
    int rl = r - g * RROWS;
    unsigned hv = (unsigned)__half_as_ushort(__float2half(aval[i]));
    unsigned w = ((unsigned)acol[i] & 0xFFFFu) | (hv << 16);
    int lpos = atomicAdd(&lcnt[g], 1);
    __syncthreads();
    if (tid < 8) lbase[tid] = atomicAdd(&qtail[tid], lcnt[tid]);
    __syncthreads();
    qdata[(size_t)g * QCAP + lbase[g] + lpos] = make_uint2(w, (unsigned)rl);
}

// ---------------- phase B: XCD-pinned drain queue -> bucket ----------------
__global__ __launch_bounds__(256) void binscatter_kernel(const int* __restrict__ qtail,
                                                         const uint2* __restrict__ qdata,
                                                         int* __restrict__ cnt,
                                                         unsigned* __restrict__ bucket) {
    const int g = blockIdx.x & 7;
    const int rank = blockIdx.x >> 3;            // 0..255 within group
    const int n = qtail[g];
    const uint2* q = qdata + (size_t)g * QCAP;
    for (int j = rank * 256 + threadIdx.x; j < n; j += (SPMM_BLOCKS / 8) * 256) {
        uint2 e = q[j];
        int r = g * RROWS + (int)e.y;
        int slot = atomicAdd(&cnt[r], 1);
        if (slot < CAP) bucket[(size_t)r * CAP + slot] = e.x;
    }
}

// ---------------- MFMA gemm: support(fp16) = fp16(input) @ Ht^T ----------------
__global__ __launch_bounds__(256) void gemm_kernel(const float* __restrict__ in,
                                                   const __half* __restrict__ Ht,
                                                   __half* __restrict__ support) {
    const int tid = threadIdx.x;
    const int wv = tid >> 6;
    const int lane = tid & 63;
    const int s = lane & 15;
    const int t = lane >> 4;

    half8 b[8][4];
#pragma unroll
    for (int kk = 0; kk < 4; ++kk)
#pragma unroll
        for (int n = 0; n < 8; ++n)
            b[n][kk] = *reinterpret_cast<const half8*>(Ht + (size_t)(16 * n + s) * D + kk * 32 + 8 * t);

    const int tile = blockIdx.x * 4 + wv;
    if (tile >= N_TILES) return;

    const float* ap = in + (size_t)(tile * 16 + s) * D;
    half8 a[4];
#pragma unroll
    for (int kk = 0; kk < 4; ++kk) {
        float4 f0 = *reinterpret_cast<const float4*>(ap + kk * 32 + 8 * t);
        float4 f1 = *reinterpret_cast<const float4*>(ap + kk * 32 + 8 * t + 4);
        a[kk][0] = (_Float16)f0.x; a[kk][1] = (_Float16)f0.y;
        a[kk][2] = (_Float16)f0.z; a[kk][3] = (_Float16)f0.w;
        a[kk][4] = (_Float16)f1.x; a[kk][5] = (_Float16)f1.y;
        a[kk][6] = (_Float16)f1.z; a[kk][7] = (_Float16)f1.w;
    }

    floatx4 acc[8];
#pragma unroll
    for (int n = 0; n < 8; ++n) acc[n] = (floatx4){0.f, 0.f, 0.f, 0.f};
#pragma unroll
    for (int kk = 0; kk < 4; ++kk)
#pragma unroll
        for (int n = 0; n < 8; ++n)
            acc[n] = __builtin_amdgcn_mfma_f32_16x16x32_f16(a[kk], b[n][kk], acc[n], 0, 0, 0);

    __half* sp = support + (size_t)(tile * 16 + 4 * t) * D + s;
#pragma unroll
    for (int r = 0; r < 4; ++r)
#pragma unroll
        for (int n = 0; n < 8; ++n)
            sp[(size_t)r * D + 16 * n] = __float2half(acc[n][r]);
}

// ---------------- XCD-sliced bucket spmm, 2 rows/wave, pk_fma_f16 ----------------
__global__ __launch_bounds__(256) void spmm_kernel(const __half* __restrict__ support,
                                                   const int* __restrict__ cnt,
                                                   const unsigned* __restrict__ bucket,
                                                   __half* __restrict__ outh,
                                                   float* __restrict__ colsum,
                                                   float* __restrict__ colsq) {
    const int tid = threadIdx.x;
    const int lane = tid & 63;
    const int wv = tid >> 6;
    const int h = lane >> 4;          // edge group 0..3
    const int cl = lane & 15;         // column lane
    const int b = blockIdx.x;
    const int slice = (b & 7) >> 1;
    const int rank = ((b >> 3) << 1) | (b & 1);   // 0..511 within slice
    const int nrank = SPMM_BLOCKS >> 2;           // 512
    const int colbase = slice * SCOLS + cl * 2;

    __shared__ float lsum[SCOLS], lsq[SCOLS];
    if (tid < SCOLS) { lsum[tid] = 0.f; lsq[tid] = 0.f; }
    __syncthreads();

    float s0 = 0.f, s1 = 0.f, q0 = 0.f, q1 = 0.f;

    for (int row = rank * 8 + wv * 2; row < N_NODES; row += nrank * 8) {
        const int rowb = row + 1;
        int na = cnt[row]; na = na < CAP ? na : CAP;
        int nb = (rowb < N_NODES) ? cnt[rowb] : 0; nb = nb < CAP ? nb : CAP;
        const unsigned ewa = (lane < na) ? bucket[(size_t)row * CAP + lane] : 0u;
        const unsigned ewb = (lane < nb) ? bucket[(size_t)rowb * CAP + lane] : 0u;
        __half2 acca = __half2half2(__ushort_as_half((unsigned short)0));
        __half2 accb = acca;
        const int nmax = na > nb ? na : nb;
        const int n16 = (nmax + 15) & ~15;
        for (int e = 0; e < n16; e += 16) {
            unsigned ua[4], ub[4];
            __half2 ga[4], gb[4];
#pragma unroll
            for (int j = 0; j < 4; ++j) {
                int idx = e + j * 4 + h;
                ua[j] = __shfl(ewa, idx);       // idx>=n lanes broadcast 0 -> col0,val0
                ub[j] = __shfl(ewb, idx);
            }
#pragma unroll
            for (int j = 0; j < 4; ++j) {
                ga[j] = *reinterpret_cast<const __half2*>(support + (size_t)(ua[j] & 0xFFFFu) * D + colbase);
                gb[j] = *reinterpret_cast<const __half2*>(support + (size_t)(ub[j] & 0xFFFFu) * D + colbase);
            }
#pragma unroll
            for (int j = 0; j < 4; ++j) {
                unsigned va2 = __builtin_amdgcn_perm(ua[j], ua[j], 0x07060706u); // (val,val)
                unsigned vb2 = __builtin_amdgcn_perm(ub[j], ub[j], 0x07060706u);
                acca = __hfma2(*reinterpret_cast<__half2*>(&va2), ga[j], acca);
                accb = __hfma2(*reinterpret_cast<__half2*>(&vb2), gb[j], accb);
            }
        }
        // combine the 4 edge groups (pk_add via bit-shuffled halves)
#pragma unroll
        for (int off = 16; off <= 32; off <<= 1) {
            int ia = __shfl_xor(*reinterpret_cast<int*>(&acca), off);
            int ib = __shfl_xor(*reinterpret_cast<int*>(&accb), off);
            acca = __hadd2(acca, *reinterpret_cast<__half2*>(&ia));
            accb = __hadd2(accb, *reinterpret_cast<__half2*>(&ib));
        }
        if (h == 0) {
            float2 fa = __half22float2(acca);
            *reinterpret_cast<__half2*>(outh + (size_t)row * D + colbase) = acca;
            s0 += fa.x; s1 += fa.y; q0 += fa.x * fa.x; q1 += fa.y * fa.y;
            if (rowb < N_NODES) {
                float2 fb = __half22float2(accb);
                *reinterpret_cast<__half2*>(outh + (size_t)rowb * D + colbase) = accb;
                s0 += fb.x; s1 += fb.y; q0 += fb.x * fb.x; q1 += fb.y * fb.y;
            }
        }
    }

    if (h == 0) {
        atomicAdd(&lsum[cl * 2 + 0], s0); atomicAdd(&lsum[cl * 2 + 1], s1);
        atomicAdd(&lsq[cl * 2 + 0], q0);  atomicAdd(&lsq[cl * 2 + 1], q1);
    }
    __syncthreads();
    if (tid < SCOLS) {
        atomicAdd(&colsum[slice * SCOLS + tid], lsum[tid]);
        atomicAdd(&colsq[slice * SCOLS + tid], lsq[tid]);
    }
}

// ---------------- BN + tanh: read fp16 outh, write fp32 out ----------------
__global__ __launch_bounds__(256) void bn_tanh_kernel(const __half* __restrict__ outh,
                                                      float* __restrict__ out,
                                                      const float* __restrict__ colsum,
                                                      const float* __restrict__ colsq,
                                                      const float* __restrict__ gamma,
                                                      const float* __restrict__ beta) {
    __shared__ float scale[D], shift[D];
    const int tid = threadIdx.x;
    if (tid < D) {
        float mean = colsum[tid] * (1.0f / N_NODES);
        float var  = colsq[tid] * (1.0f / N_NODES) - mean * mean;
        float sc   = rsqrtf(var + BN_EPS) * gamma[tid];
        scale[tid] = sc;
        shift[tid] = beta[tid] - mean * sc;
    }
    __syncthreads();
    const int nq = N_NODES * D / 8;   // units of 8 halves
    for (int i = blockIdx.x * 256 + tid; i < nq; i += gridDim.x * 256) {
        uint4 v = reinterpret_cast<const uint4*>(outh)[i];
        const int c = (i & 15) * 8;
        float r[8];
        float2 f;
        f = __half22float2(*reinterpret_cast<__half2*>(&v.x)); r[0] = f.x; r[1] = f.y;
        f = __half22float2(*reinterpret_cast<__half2*>(&v.y)); r[2] = f.x; r[3] = f.y;
        f = __half22float2(*reinterpret_cast<__half2*>(&v.z)); r[4] = f.x; r[5] = f.y;
        f = __half22float2(*reinterpret_cast<__half2*>(&v.w)); r[6] = f.x; r[7] = f.y;
#pragma unroll
        for (int k = 0; k < 8; ++k) {
            float x = r[k] * scale[c + k] + shift[c + k];
            float e = __expf(2.0f * x);
            r[k] = 1.0f - 2.0f / (1.0f + e);
        }
        float4 o0 = make_float4(r[0], r[1], r[2], r[3]);
        float4 o1 = make_float4(r[4], r[5], r[6], r[7]);
        reinterpret_cast<float4*>(out)[i * 2 + 0] = o0;
        reinterpret_cast<float4*>(out)[i * 2 + 1] = o1;
    }
}

// ---------------- launch ----------------
extern "C" void kernel_launch(void* const* d_in, const int* in_sizes, int n_in,
                              void* d_out, int out_size, void* d_ws, size_t ws_size,
                              hipStream_t stream) {
    const float* input  = (const float*)d_in[0];
    const int*   arow   = (const int*)d_in[1];
    const int*   acol   = (const int*)d_in[2];
    const float* aval   = (const float*)d_in[3];
    const float* weight = (const float*)d_in[4];
    const float* gamma  = (const float*)d_in[5];
    const float* beta   = (const float*)d_in[6];
    float* out = (float*)d_out;

    __half*   support = (__half*)d_ws;                              // 12.8 MB
    unsigned* bucket  = (unsigned*)(support + (size_t)N_NODES * D); // 12.8 MB
    __half*   outh    = (__half*)(bucket + (size_t)N_NODES * CAP);  // 12.8 MB
    uint2*    qdata   = (uint2*)outh;                               // aliases outh (consumed before spmm writes)
    int*      cnt     = (int*)(outh + (size_t)N_NODES * D);         // 200 KB
    float*    colsum  = (float*)(cnt + N_NODES);                    // 128 (+128 colsq)
    int*      qtail   = (int*)(colsum + 2 * D);                     // 8
    __half*   Ht      = (__half*)(qtail + 8);                       // 32 KB

    setup_kernel<<<196, 256, 0, stream>>>(weight, Ht, cnt, colsum, qtail);
    bin_kernel<<<N_EDGES / 256, 256, 0, stream>>>(arow, acol, aval, qtail, qdata);
    binscatter_kernel<<<SPMM_BLOCKS, 256, 0, stream>>>(qtail, qdata, cnt, bucket);
    gemm_kernel<<<(N_TILES + 3) / 4, 256, 0, stream>>>(input, Ht, support);
    spmm_kernel<<<SPMM_BLOCKS, 256, 0, stream>>>(support, cnt, bucket, outh, colsum, colsum + D);
    bn_tanh_kernel<<<2048, 256, 0, stream>>>(outh, out, colsum, colsum + D, gamma, beta);
}

// Round 10
// 132.353 us; speedup vs baseline: 1.1973x; 1.1973x over previous
//
#include <hip/hip_runtime.h>
#include <hip/hip_fp16.h>
#include <math.h>

#define N_NODES 50000
#define N_EDGES 800000
#define D 128
#define BN_EPS 1e-5f
#define N_TILES 3125   // 50000 / 16
#define CAP 64         // max degree capacity (Poisson(16); P(deg>64) ~ 1e-19)
#define SPMM_BLOCKS 2048
#define SCOLS 32       // columns per XCD-pinned slice (3.2 MB fp16 -> fits 4 MiB L2)
#define RROWS 6250     // N_NODES / 8: rows per XCD group

typedef __attribute__((ext_vector_type(8))) _Float16 half8;
typedef __attribute__((ext_vector_type(4))) float floatx4;

// ---------------- octonion Hamilton tables ----------------
__device__ __constant__ int OCT_C[8][8] = {
    {0,1,2,3,4,5,6,7},
    {1,0,3,2,5,4,7,6},
    {2,3,0,1,6,7,4,5},
    {3,2,1,0,7,6,5,4},
    {4,5,6,7,0,1,2,3},
    {5,4,7,6,1,0,3,2},
    {6,7,4,5,2,3,0,1},
    {7,6,5,4,3,2,1,0}};
__device__ __constant__ float OCT_S[8][8] = {
    { 1,-1,-1,-1,-1,-1,-1,-1},
    { 1, 1,-1, 1,-1, 1, 1,-1},
    { 1, 1, 1,-1,-1,-1, 1, 1},
    { 1,-1, 1, 1,-1, 1,-1, 1},
    { 1, 1, 1, 1, 1,-1,-1,-1},
    { 1,-1, 1,-1, 1, 1, 1,-1},
    { 1,-1,-1, 1, 1,-1, 1, 1},
    { 1, 1,-1,-1, 1, 1,-1, 1}};

// ---------------- setup: build Ht + zero cnt/stats ----------------
__global__ void setup_kernel(const float* __restrict__ W, __half* __restrict__ Ht,
                             int* __restrict__ cnt, float* __restrict__ stats) {
    int i = blockIdx.x * 256 + threadIdx.x;
    if (i < D * D) {
        int ccol = i >> 7, k = i & 127;
        int ii = k >> 4, kw = k & 15, j = ccol >> 4, m = ccol & 15;
        Ht[i] = __float2half(OCT_S[j][ii] * W[kw * D + OCT_C[j][ii] * 16 + m]);
    }
    if (i < N_NODES) cnt[i] = 0;
    if (i < 2 * D) stats[i] = 0.0f;
}

// ---------------- pack: epack[i] = (col | half(val)<<16, row) once, coalesced ----------------
__global__ __launch_bounds__(256) void pack_kernel(const int* __restrict__ arow,
                                                   const int* __restrict__ acol,
                                                   const float* __restrict__ aval,
                                                   uint2* __restrict__ epack) {
    const int base = (blockIdx.x * 256 + threadIdx.x) * 4;
    if (base + 4 <= N_EDGES) {
        int4   r4 = *reinterpret_cast<const int4*>(arow + base);
        int4   c4 = *reinterpret_cast<const int4*>(acol + base);
        float4 v4 = *reinterpret_cast<const float4*>(aval + base);
        uint2 o[4];
        o[0] = make_uint2(((unsigned)c4.x & 0xFFFFu) | ((unsigned)__half_as_ushort(__float2half(v4.x)) << 16), (unsigned)r4.x);
        o[1] = make_uint2(((unsigned)c4.y & 0xFFFFu) | ((unsigned)__half_as_ushort(__float2half(v4.y)) << 16), (unsigned)r4.y);
        o[2] = make_uint2(((unsigned)c4.z & 0xFFFFu) | ((unsigned)__half_as_ushort(__float2half(v4.z)) << 16), (unsigned)r4.z);
        o[3] = make_uint2(((unsigned)c4.w & 0xFFFFu) | ((unsigned)__half_as_ushort(__float2half(v4.w)) << 16), (unsigned)r4.w);
        reinterpret_cast<uint4*>(epack + base)[0] = *reinterpret_cast<uint4*>(&o[0]);
        reinterpret_cast<uint4*>(epack + base)[1] = *reinterpret_cast<uint4*>(&o[2]);
    }
}

// ---------------- XCD-pinned bucket scatter (nontemporal streaming reread) ----------------
__global__ __launch_bounds__(256) void scatter_kernel(const uint2* __restrict__ epack,
                                                      int* __restrict__ cnt,
                                                      unsigned* __restrict__ bucket) {
    const int g = blockIdx.x & 7;
    const int rank = blockIdx.x >> 3;            // 0..255 within group
    const int r0 = g * RROWS, r1 = r0 + RROWS;
    const unsigned long long* ep = reinterpret_cast<const unsigned long long*>(epack);
    for (int i = rank * 256 + threadIdx.x; i < N_EDGES; i += (SPMM_BLOCKS / 8) * 256) {
        unsigned long long e = __builtin_nontemporal_load(ep + i);
        int r = (int)(e >> 32);
        if (r >= r0 && r < r1) {
            int slot = atomicAdd(&cnt[r], 1);
            if (slot < CAP) bucket[(size_t)r * CAP + slot] = (unsigned)e;
        }
    }
}

// ---------------- MFMA gemm: support(fp16) = fp16(input) @ Ht^T ----------------
__global__ __launch_bounds__(256) void gemm_kernel(const float* __restrict__ in,
                                                   const __half* __restrict__ Ht,
                                                   __half* __restrict__ support) {
    const int tid = threadIdx.x;
    const int wv = tid >> 6;
    const int lane = tid & 63;
    const int s = lane & 15;
    const int t = lane >> 4;

    half8 b[8][4];
#pragma unroll
    for (int kk = 0; kk < 4; ++kk)
#pragma unroll
        for (int n = 0; n < 8; ++n)
            b[n][kk] = *reinterpret_cast<const half8*>(Ht + (size_t)(16 * n + s) * D + kk * 32 + 8 * t);

    const int tile = blockIdx.x * 4 + wv;
    if (tile >= N_TILES) return;

    const float* ap = in + (size_t)(tile * 16 + s) * D;
    half8 a[4];
#pragma unroll
    for (int kk = 0; kk < 4; ++kk) {
        float4 f0 = *reinterpret_cast<const float4*>(ap + kk * 32 + 8 * t);
        float4 f1 = *reinterpret_cast<const float4*>(ap + kk * 32 + 8 * t + 4);
        a[kk][0] = (_Float16)f0.x; a[kk][1] = (_Float16)f0.y;
        a[kk][2] = (_Float16)f0.z; a[kk][3] = (_Float16)f0.w;
        a[kk][4] = (_Float16)f1.x; a[kk][5] = (_Float16)f1.y;
        a[kk][6] = (_Float16)f1.z; a[kk][7] = (_Float16)f1.w;
    }

    floatx4 acc[8];
#pragma unroll
    for (int n = 0; n < 8; ++n) acc[n] = (floatx4){0.f, 0.f, 0.f, 0.f};
#pragma unroll
    for (int kk = 0; kk < 4; ++kk)
#pragma unroll
        for (int n = 0; n < 8; ++n)
            acc[n] = __builtin_amdgcn_mfma_f32_16x16x32_f16(a[kk], b[n][kk], acc[n], 0, 0, 0);

    __half* sp = support + (size_t)(tile * 16 + 4 * t) * D + s;
#pragma unroll
    for (int r = 0; r < 4; ++r)
#pragma unroll
        for (int n = 0; n < 8; ++n)
            sp[(size_t)r * D + 16 * n] = __float2half(acc[n][r]);
}

// ---------------- XCD-sliced bucket spmm, 2 rows/wave, pk_fma_f16, nontemporal streams ----------------
__global__ __launch_bounds__(256) void spmm_kernel(const __half* __restrict__ support,
                                                   const int* __restrict__ cnt,
                                                   const unsigned* __restrict__ bucket,
                                                   __half* __restrict__ outh,
                                                   float* __restrict__ colsum,
                                                   float* __restrict__ colsq) {
    const int tid = threadIdx.x;
    const int lane = tid & 63;
    const int wv = tid >> 6;
    const int h = lane >> 4;          // edge group 0..3
    const int cl = lane & 15;         // column lane
    const int b = blockIdx.x;
    const int slice = (b & 7) >> 1;
    const int rank = ((b >> 3) << 1) | (b & 1);   // 0..511 within slice
    const int nrank = SPMM_BLOCKS >> 2;           // 512
    const int colbase = slice * SCOLS + cl * 2;

    __shared__ float lsum[SCOLS], lsq[SCOLS];
    if (tid < SCOLS) { lsum[tid] = 0.f; lsq[tid] = 0.f; }
    __syncthreads();

    float s0 = 0.f, s1 = 0.f, q0 = 0.f, q1 = 0.f;

    for (int row = rank * 8 + wv * 2; row < N_NODES; row += nrank * 8) {
        const int rowb = row + 1;
        int na = cnt[row]; na = na < CAP ? na : CAP;
        int nb = (rowb < N_NODES) ? cnt[rowb] : 0; nb = nb < CAP ? nb : CAP;
        const unsigned ewa = (lane < na) ? __builtin_nontemporal_load(bucket + (size_t)row * CAP + lane) : 0u;
        const unsigned ewb = (lane < nb) ? __builtin_nontemporal_load(bucket + (size_t)rowb * CAP + lane) : 0u;
        __half2 acca = __half2half2(__ushort_as_half((unsigned short)0));
        __half2 accb = acca;
        const int nmax = na > nb ? na : nb;
        const int n16 = (nmax + 15) & ~15;
        for (int e = 0; e < n16; e += 16) {
            unsigned ua[4], ub[4];
            __half2 ga[4], gb[4];
#pragma unroll
            for (int j = 0; j < 4; ++j) {
                int idx = e + j * 4 + h;
                ua[j] = __shfl(ewa, idx);       // idx>=n lanes broadcast 0 -> col0,val0
                ub[j] = __shfl(ewb, idx);
            }
#pragma unroll
            for (int j = 0; j < 4; ++j) {
                ga[j] = *reinterpret_cast<const __half2*>(support + (size_t)(ua[j] & 0xFFFFu) * D + colbase);
                gb[j] = *reinterpret_cast<const __half2*>(support + (size_t)(ub[j] & 0xFFFFu) * D + colbase);
            }
#pragma unroll
            for (int j = 0; j < 4; ++j) {
                unsigned va2 = __builtin_amdgcn_perm(ua[j], ua[j], 0x07060706u); // (val,val)
                unsigned vb2 = __builtin_amdgcn_perm(ub[j], ub[j], 0x07060706u);
                acca = __hfma2(*reinterpret_cast<__half2*>(&va2), ga[j], acca);
                accb = __hfma2(*reinterpret_cast<__half2*>(&vb2), gb[j], accb);
            }
        }
        // combine the 4 edge groups
#pragma unroll
        for (int off = 16; off <= 32; off <<= 1) {
            int ia = __shfl_xor(*reinterpret_cast<int*>(&acca), off);
            int ib = __shfl_xor(*reinterpret_cast<int*>(&accb), off);
            acca = __hadd2(acca, *reinterpret_cast<__half2*>(&ia));
            accb = __hadd2(accb, *reinterpret_cast<__half2*>(&ib));
        }
        if (h == 0) {
            float2 fa = __half22float2(acca);
            __builtin_nontemporal_store(*reinterpret_cast<unsigned*>(&acca),
                reinterpret_cast<unsigned*>(outh + (size_t)row * D + colbase));
            s0 += fa.x; s1 += fa.y; q0 += fa.x * fa.x; q1 += fa.y * fa.y;
            if (rowb < N_NODES) {
                float2 fb = __half22float2(accb);
                __builtin_nontemporal_store(*reinterpret_cast<unsigned*>(&accb),
                    reinterpret_cast<unsigned*>(outh + (size_t)rowb * D + colbase));
                s0 += fb.x; s1 += fb.y; q0 += fb.x * fb.x; q1 += fb.y * fb.y;
            }
        }
    }

    if (h == 0) {
        atomicAdd(&lsum[cl * 2 + 0], s0); atomicAdd(&lsum[cl * 2 + 1], s1);
        atomicAdd(&lsq[cl * 2 + 0], q0);  atomicAdd(&lsq[cl * 2 + 1], q1);
    }
    __syncthreads();
    if (tid < SCOLS) {
        atomicAdd(&colsum[slice * SCOLS + tid], lsum[tid]);
        atomicAdd(&colsq[slice * SCOLS + tid], lsq[tid]);
    }
}

// ---------------- BN + tanh: read fp16 outh, write fp32 out ----------------
__global__ __launch_bounds__(256) void bn_tanh_kernel(const __half* __restrict__ outh,
                                                      float* __restrict__ out,
                                                      const float* __restrict__ colsum,
                                                      const float* __restrict__ colsq,
                                                      const float* __restrict__ gamma,
                                                      const float* __restrict__ beta) {
    __shared__ float scale[D], shift[D];
    const int tid = threadIdx.x;
    if (tid < D) {
        float mean = colsum[tid] * (1.0f / N_NODES);
        float var  = colsq[tid] * (1.0f / N_NODES) - mean * mean;
        float sc   = rsqrtf(var + BN_EPS) * gamma[tid];
        scale[tid] = sc;
        shift[tid] = beta[tid] - mean * sc;
    }
    __syncthreads();
    const int nq = N_NODES * D / 8;   // units of 8 halves
    for (int i = blockIdx.x * 256 + tid; i < nq; i += gridDim.x * 256) {
        uint4 v = reinterpret_cast<const uint4*>(outh)[i];
        const int c = (i & 15) * 8;
        float r[8];
        float2 f;
        f = __half22float2(*reinterpret_cast<__half2*>(&v.x)); r[0] = f.x; r[1] = f.y;
        f = __half22float2(*reinterpret_cast<__half2*>(&v.y)); r[2] = f.x; r[3] = f.y;
        f = __half22float2(*reinterpret_cast<__half2*>(&v.z)); r[4] = f.x; r[5] = f.y;
        f = __half22float2(*reinterpret_cast<__half2*>(&v.w)); r[6] = f.x; r[7] = f.y;
#pragma unroll
        for (int k = 0; k < 8; ++k) {
            float x = r[k] * scale[c + k] + shift[c + k];
            float e = __expf(2.0f * x);
            r[k] = 1.0f - 2.0f / (1.0f + e);
        }
        float4 o0 = make_float4(r[0], r[1], r[2], r[3]);
        float4 o1 = make_float4(r[4], r[5], r[6], r[7]);
        reinterpret_cast<float4*>(out)[i * 2 + 0] = o0;
        reinterpret_cast<float4*>(out)[i * 2 + 1] = o1;
    }
}

// ---------------- launch ----------------
extern "C" void kernel_launch(void* const* d_in, const int* in_sizes, int n_in,
                              void* d_out, int out_size, void* d_ws, size_t ws_size,
                              hipStream_t stream) {
    const float* input  = (const float*)d_in[0];
    const int*   arow   = (const int*)d_in[1];
    const int*   acol   = (const int*)d_in[2];
    const float* aval   = (const float*)d_in[3];
    const float* weight = (const float*)d_in[4];
    const float* gamma  = (const float*)d_in[5];
    const float* beta   = (const float*)d_in[6];
    float* out = (float*)d_out;

    __half*   support = (__half*)d_ws;                              // 12.8 MB
    unsigned* bucket  = (unsigned*)(support + (size_t)N_NODES * D); // 12.8 MB
    __half*   outh    = (__half*)(bucket + (size_t)N_NODES * CAP);  // 12.8 MB
    uint2*    epack   = (uint2*)outh;                               // aliases outh (consumed before spmm writes)
    int*      cnt     = (int*)(outh + (size_t)N_NODES * D);         // 200 KB
    float*    colsum  = (float*)(cnt + N_NODES);                    // 128 (+128 colsq)
    __half*   Ht      = (__half*)(colsum + 2 * D);                  // 32 KB

    setup_kernel<<<196, 256, 0, stream>>>(weight, Ht, cnt, colsum);
    pack_kernel<<<(N_EDGES / 4 + 255) / 256, 256, 0, stream>>>(arow, acol, aval, epack);
    scatter_kernel<<<SPMM_BLOCKS, 256, 0, stream>>>(epack, cnt, bucket);
    gemm_kernel<<<(N_TILES + 3) / 4, 256, 0, stream>>>(input, Ht, support);
    spmm_kernel<<<SPMM_BLOCKS, 256, 0, stream>>>(support, cnt, bucket, outh, colsum, colsum + D);
    bn_tanh_kernel<<<2048, 256, 0, stream>>>(outh, out, colsum, colsum + D, gamma, beta);
}

// Round 11
// 125.208 us; speedup vs baseline: 1.2656x; 1.0571x over previous
//
#include <hip/hip_runtime.h>
#include <hip/hip_fp16.h>
#include <math.h>

#define N_NODES 50000
#define N_EDGES 800000
#define D 128
#define BN_EPS 1e-5f
#define N_TILES 3125   // 50000 / 16
#define CAP 64         // max degree capacity (Poisson(16); P(deg>64) ~ 1e-19)
#define SPMM_BLOCKS 2048
#define SCOLS 32       // columns per XCD-pinned slice (3.2 MB fp16 -> fits 4 MiB L2)
#define RROWS 6250     // N_NODES / 8: rows per XCD group
#define GEMM_BLOCKS 782  // ceil(3125/4)

typedef __attribute__((ext_vector_type(8))) _Float16 half8;
typedef __attribute__((ext_vector_type(4))) float floatx4;

// ---------------- octonion Hamilton tables ----------------
__device__ __constant__ int OCT_C[8][8] = {
    {0,1,2,3,4,5,6,7},
    {1,0,3,2,5,4,7,6},
    {2,3,0,1,6,7,4,5},
    {3,2,1,0,7,6,5,4},
    {4,5,6,7,0,1,2,3},
    {5,4,7,6,1,0,3,2},
    {6,7,4,5,2,3,0,1},
    {7,6,5,4,3,2,1,0}};
__device__ __constant__ float OCT_S[8][8] = {
    { 1,-1,-1,-1,-1,-1,-1,-1},
    { 1, 1,-1, 1,-1, 1, 1,-1},
    { 1, 1, 1,-1,-1,-1, 1, 1},
    { 1,-1, 1, 1,-1, 1,-1, 1},
    { 1, 1, 1, 1, 1,-1,-1,-1},
    { 1,-1, 1,-1, 1, 1, 1,-1},
    { 1,-1,-1, 1, 1,-1, 1, 1},
    { 1, 1,-1,-1, 1, 1,-1, 1}};

// ---------------- k1: setup (Ht, zero cnt/stats) + pack epack ----------------
__global__ __launch_bounds__(256) void setup_pack_kernel(const float* __restrict__ W,
                                                         __half* __restrict__ Ht,
                                                         int* __restrict__ cnt,
                                                         float* __restrict__ stats,
                                                         const int* __restrict__ arow,
                                                         const int* __restrict__ acol,
                                                         const float* __restrict__ aval,
                                                         uint2* __restrict__ epack) {
    const int i = blockIdx.x * 256 + threadIdx.x;
    if (i < D * D) {
        int ccol = i >> 7, k = i & 127;
        int ii = k >> 4, kw = k & 15, j = ccol >> 4, m = ccol & 15;
        Ht[i] = __float2half(OCT_S[j][ii] * W[kw * D + OCT_C[j][ii] * 16 + m]);
    }
    if (i < N_NODES) cnt[i] = 0;
    if (i < 2 * D) stats[i] = 0.0f;
    const int base = i * 4;
    if (base + 4 <= N_EDGES) {
        int4   r4 = *reinterpret_cast<const int4*>(arow + base);
        int4   c4 = *reinterpret_cast<const int4*>(acol + base);
        float4 v4 = *reinterpret_cast<const float4*>(aval + base);
        uint2 o[4];
        o[0] = make_uint2(((unsigned)c4.x & 0xFFFFu) | ((unsigned)__half_as_ushort(__float2half(v4.x)) << 16), (unsigned)r4.x);
        o[1] = make_uint2(((unsigned)c4.y & 0xFFFFu) | ((unsigned)__half_as_ushort(__float2half(v4.y)) << 16), (unsigned)r4.y);
        o[2] = make_uint2(((unsigned)c4.z & 0xFFFFu) | ((unsigned)__half_as_ushort(__float2half(v4.z)) << 16), (unsigned)r4.z);
        o[3] = make_uint2(((unsigned)c4.w & 0xFFFFu) | ((unsigned)__half_as_ushort(__float2half(v4.w)) << 16), (unsigned)r4.w);
        reinterpret_cast<uint4*>(epack + base)[0] = *reinterpret_cast<uint4*>(&o[0]);
        reinterpret_cast<uint4*>(epack + base)[1] = *reinterpret_cast<uint4*>(&o[2]);
    }
}

// ---------------- k2: fused scatter (blocks 0..2047) + gemm (blocks 2048..2829) ----------------
// scatter: XCD-pinned bucket fill; gemm: MFMA support = fp16(input) @ Ht^T.
// Independent data; co-resident waves overlap the memory-bound scatter with the
// MFMA-bound gemm so the stage costs ~max() not sum().
__global__ __launch_bounds__(256) void gemm_scatter_kernel(const uint2* __restrict__ epack,
                                                           int* __restrict__ cnt,
                                                           unsigned* __restrict__ bucket,
                                                           const float* __restrict__ in,
                                                           const __half* __restrict__ Ht,
                                                           __half* __restrict__ support) {
    const int b = blockIdx.x;
    if (b < SPMM_BLOCKS) {
        // ---- scatter ----
        const int g = b & 7;
        const int rank = b >> 3;                 // 0..255 within group
        const int r0 = g * RROWS, r1 = r0 + RROWS;
        const unsigned long long* ep = reinterpret_cast<const unsigned long long*>(epack);
        for (int i = rank * 256 + threadIdx.x; i < N_EDGES; i += (SPMM_BLOCKS / 8) * 256) {
            unsigned long long e = __builtin_nontemporal_load(ep + i);
            int r = (int)(e >> 32);
            if (r >= r0 && r < r1) {
                int slot = atomicAdd(&cnt[r], 1);
                if (slot < CAP) bucket[(size_t)r * CAP + slot] = (unsigned)e;
            }
        }
        return;
    }
    // ---- gemm ----
    const int tid = threadIdx.x;
    const int wv = tid >> 6;
    const int lane = tid & 63;
    const int s = lane & 15;
    const int t = lane >> 4;

    half8 bb[8][4];
#pragma unroll
    for (int kk = 0; kk < 4; ++kk)
#pragma unroll
        for (int n = 0; n < 8; ++n)
            bb[n][kk] = *reinterpret_cast<const half8*>(Ht + (size_t)(16 * n + s) * D + kk * 32 + 8 * t);

    const int tile = (b - SPMM_BLOCKS) * 4 + wv;
    if (tile >= N_TILES) return;

    const float* ap = in + (size_t)(tile * 16 + s) * D;
    half8 a[4];
#pragma unroll
    for (int kk = 0; kk < 4; ++kk) {
        float4 f0 = *reinterpret_cast<const float4*>(ap + kk * 32 + 8 * t);
        float4 f1 = *reinterpret_cast<const float4*>(ap + kk * 32 + 8 * t + 4);
        a[kk][0] = (_Float16)f0.x; a[kk][1] = (_Float16)f0.y;
        a[kk][2] = (_Float16)f0.z; a[kk][3] = (_Float16)f0.w;
        a[kk][4] = (_Float16)f1.x; a[kk][5] = (_Float16)f1.y;
        a[kk][6] = (_Float16)f1.z; a[kk][7] = (_Float16)f1.w;
    }

    floatx4 acc[8];
#pragma unroll
    for (int n = 0; n < 8; ++n) acc[n] = (floatx4){0.f, 0.f, 0.f, 0.f};
#pragma unroll
    for (int kk = 0; kk < 4; ++kk)
#pragma unroll
        for (int n = 0; n < 8; ++n)
            acc[n] = __builtin_amdgcn_mfma_f32_16x16x32_f16(a[kk], bb[n][kk], acc[n], 0, 0, 0);

    __half* sp = support + (size_t)(tile * 16 + 4 * t) * D + s;
#pragma unroll
    for (int r = 0; r < 4; ++r)
#pragma unroll
        for (int n = 0; n < 8; ++n)
            sp[(size_t)r * D + 16 * n] = __float2half(acc[n][r]);
}

// ---------------- XCD-sliced bucket spmm, 2 rows/wave, pk_fma_f16 (R9 form) ----------------
__global__ __launch_bounds__(256) void spmm_kernel(const __half* __restrict__ support,
                                                   const int* __restrict__ cnt,
                                                   const unsigned* __restrict__ bucket,
                                                   __half* __restrict__ outh,
                                                   float* __restrict__ colsum,
                                                   float* __restrict__ colsq) {
    const int tid = threadIdx.x;
    const int lane = tid & 63;
    const int wv = tid >> 6;
    const int h = lane >> 4;          // edge group 0..3
    const int cl = lane & 15;         // column lane
    const int b = blockIdx.x;
    const int slice = (b & 7) >> 1;
    const int rank = ((b >> 3) << 1) | (b & 1);   // 0..511 within slice
    const int nrank = SPMM_BLOCKS >> 2;           // 512
    const int colbase = slice * SCOLS + cl * 2;

    __shared__ float lsum[SCOLS], lsq[SCOLS];
    if (tid < SCOLS) { lsum[tid] = 0.f; lsq[tid] = 0.f; }
    __syncthreads();

    float s0 = 0.f, s1 = 0.f, q0 = 0.f, q1 = 0.f;

    for (int row = rank * 8 + wv * 2; row < N_NODES; row += nrank * 8) {
        const int rowb = row + 1;
        int na = cnt[row]; na = na < CAP ? na : CAP;
        int nb = (rowb < N_NODES) ? cnt[rowb] : 0; nb = nb < CAP ? nb : CAP;
        const unsigned ewa = (lane < na) ? bucket[(size_t)row * CAP + lane] : 0u;
        const unsigned ewb = (lane < nb) ? bucket[(size_t)rowb * CAP + lane] : 0u;
        __half2 acca = __half2half2(__ushort_as_half((unsigned short)0));
        __half2 accb = acca;
        const int nmax = na > nb ? na : nb;
        const int n16 = (nmax + 15) & ~15;
        for (int e = 0; e < n16; e += 16) {
            unsigned ua[4], ub[4];
            __half2 ga[4], gb[4];
#pragma unroll
            for (int j = 0; j < 4; ++j) {
                int idx = e + j * 4 + h;
                ua[j] = __shfl(ewa, idx);       // idx>=n lanes broadcast 0 -> col0,val0
                ub[j] = __shfl(ewb, idx);
            }
#pragma unroll
            for (int j = 0; j < 4; ++j) {
                ga[j] = *reinterpret_cast<const __half2*>(support + (size_t)(ua[j] & 0xFFFFu) * D + colbase);
                gb[j] = *reinterpret_cast<const __half2*>(support + (size_t)(ub[j] & 0xFFFFu) * D + colbase);
            }
#pragma unroll
            for (int j = 0; j < 4; ++j) {
                unsigned va2 = __builtin_amdgcn_perm(ua[j], ua[j], 0x07060706u); // (val,val)
                unsigned vb2 = __builtin_amdgcn_perm(ub[j], ub[j], 0x07060706u);
                acca = __hfma2(*reinterpret_cast<__half2*>(&va2), ga[j], acca);
                accb = __hfma2(*reinterpret_cast<__half2*>(&vb2), gb[j], accb);
            }
        }
        // combine the 4 edge groups
#pragma unroll
        for (int off = 16; off <= 32; off <<= 1) {
            int ia = __shfl_xor(*reinterpret_cast<int*>(&acca), off);
            int ib = __shfl_xor(*reinterpret_cast<int*>(&accb), off);
            acca = __hadd2(acca, *reinterpret_cast<__half2*>(&ia));
            accb = __hadd2(accb, *reinterpret_cast<__half2*>(&ib));
        }
        if (h == 0) {
            float2 fa = __half22float2(acca);
            *reinterpret_cast<__half2*>(outh + (size_t)row * D + colbase) = acca;
            s0 += fa.x; s1 += fa.y; q0 += fa.x * fa.x; q1 += fa.y * fa.y;
            if (rowb < N_NODES) {
                float2 fb = __half22float2(accb);
                *reinterpret_cast<__half2*>(outh + (size_t)rowb * D + colbase) = accb;
                s0 += fb.x; s1 += fb.y; q0 += fb.x * fb.x; q1 += fb.y * fb.y;
            }
        }
    }

    if (h == 0) {
        atomicAdd(&lsum[cl * 2 + 0], s0); atomicAdd(&lsum[cl * 2 + 1], s1);
        atomicAdd(&lsq[cl * 2 + 0], q0);  atomicAdd(&lsq[cl * 2 + 1], q1);
    }
    __syncthreads();
    if (tid < SCOLS) {
        atomicAdd(&colsum[slice * SCOLS + tid], lsum[tid]);
        atomicAdd(&colsq[slice * SCOLS + tid], lsq[tid]);
    }
}

// ---------------- BN + tanh: read fp16 outh, write fp32 out ----------------
__global__ __launch_bounds__(256) void bn_tanh_kernel(const __half* __restrict__ outh,
                                                      float* __restrict__ out,
                                                      const float* __restrict__ colsum,
                                                      const float* __restrict__ colsq,
                                                      const float* __restrict__ gamma,
                                                      const float* __restrict__ beta) {
    __shared__ float scale[D], shift[D];
    const int tid = threadIdx.x;
    if (tid < D) {
        float mean = colsum[tid] * (1.0f / N_NODES);
        float var  = colsq[tid] * (1.0f / N_NODES) - mean * mean;
        float sc   = rsqrtf(var + BN_EPS) * gamma[tid];
        scale[tid] = sc;
        shift[tid] = beta[tid] - mean * sc;
    }
    __syncthreads();
    const int nq = N_NODES * D / 8;   // units of 8 halves
    for (int i = blockIdx.x * 256 + tid; i < nq; i += gridDim.x * 256) {
        uint4 v = reinterpret_cast<const uint4*>(outh)[i];
        const int c = (i & 15) * 8;
        float r[8];
        float2 f;
        f = __half22float2(*reinterpret_cast<__half2*>(&v.x)); r[0] = f.x; r[1] = f.y;
        f = __half22float2(*reinterpret_cast<__half2*>(&v.y)); r[2] = f.x; r[3] = f.y;
        f = __half22float2(*reinterpret_cast<__half2*>(&v.z)); r[4] = f.x; r[5] = f.y;
        f = __half22float2(*reinterpret_cast<__half2*>(&v.w)); r[6] = f.x; r[7] = f.y;
#pragma unroll
        for (int k = 0; k < 8; ++k) {
            float x = r[k] * scale[c + k] + shift[c + k];
            float e = __expf(2.0f * x);
            r[k] = 1.0f - 2.0f / (1.0f + e);
        }
        float4 o0 = make_float4(r[0], r[1], r[2], r[3]);
        float4 o1 = make_float4(r[4], r[5], r[6], r[7]);
        reinterpret_cast<float4*>(out)[i * 2 + 0] = o0;
        reinterpret_cast<float4*>(out)[i * 2 + 1] = o1;
    }
}

// ---------------- launch ----------------
extern "C" void kernel_launch(void* const* d_in, const int* in_sizes, int n_in,
                              void* d_out, int out_size, void* d_ws, size_t ws_size,
                              hipStream_t stream) {
    const float* input  = (const float*)d_in[0];
    const int*   arow   = (const int*)d_in[1];
    const int*   acol   = (const int*)d_in[2];
    const float* aval   = (const float*)d_in[3];
    const float* weight = (const float*)d_in[4];
    const float* gamma  = (const float*)d_in[5];
    const float* beta   = (const float*)d_in[6];
    float* out = (float*)d_out;

    __half*   support = (__half*)d_ws;                              // 12.8 MB
    unsigned* bucket  = (unsigned*)(support + (size_t)N_NODES * D); // 12.8 MB
    __half*   outh    = (__half*)(bucket + (size_t)N_NODES * CAP);  // 12.8 MB
    uint2*    epack   = (uint2*)outh;                               // aliases outh (consumed before spmm writes)
    int*      cnt     = (int*)(outh + (size_t)N_NODES * D);         // 200 KB
    float*    colsum  = (float*)(cnt + N_NODES);                    // 128 (+128 colsq)
    __half*   Ht      = (__half*)(colsum + 2 * D);                  // 32 KB

    setup_pack_kernel<<<GEMM_BLOCKS, 256, 0, stream>>>(weight, Ht, cnt, colsum,
                                                       arow, acol, aval, epack);
    gemm_scatter_kernel<<<SPMM_BLOCKS + GEMM_BLOCKS, 256, 0, stream>>>(epack, cnt, bucket,
                                                                       input, Ht, support);
    spmm_kernel<<<SPMM_BLOCKS, 256, 0, stream>>>(support, cnt, bucket, outh, colsum, colsum + D);
    bn_tanh_kernel<<<2048, 256, 0, stream>>>(outh, out, colsum, colsum + D, gamma, beta);
}

// Round 12
// 111.208 us; speedup vs baseline: 1.4250x; 1.1259x over previous
//
#include <hip/hip_runtime.h>
#include <hip/hip_fp16.h>
#include <math.h>

#define N_NODES 50000
#define N_EDGES 800000
#define D 128
#define BN_EPS 1e-5f
#define N_TILES 3125   // 50000 / 16
#define CAP 64         // max degree capacity (Poisson(16); P(deg>64) ~ 1e-19)
#define SPMM_BLOCKS 2048
#define SCOLS 32       // columns per XCD-pinned slice (3.2 MB fp16 -> fits 4 MiB L2)
#define RROWS 6250     // N_NODES / 8: rows per XCD group
#define SC_THREADS 384 // scatter threads per block (waves 2..7)
#define SC_STRIDE (256 * SC_THREADS)   // 98304 lanes per XCD group

typedef __attribute__((ext_vector_type(8))) _Float16 half8;
typedef __attribute__((ext_vector_type(4))) float floatx4;

// ---------------- octonion Hamilton tables ----------------
__device__ __constant__ int OCT_C[8][8] = {
    {0,1,2,3,4,5,6,7},
    {1,0,3,2,5,4,7,6},
    {2,3,0,1,6,7,4,5},
    {3,2,1,0,7,6,5,4},
    {4,5,6,7,0,1,2,3},
    {5,4,7,6,1,0,3,2},
    {6,7,4,5,2,3,0,1},
    {7,6,5,4,3,2,1,0}};
__device__ __constant__ float OCT_S[8][8] = {
    { 1,-1,-1,-1,-1,-1,-1,-1},
    { 1, 1,-1, 1,-1, 1, 1,-1},
    { 1, 1, 1,-1,-1,-1, 1, 1},
    { 1,-1, 1, 1,-1, 1,-1, 1},
    { 1, 1, 1, 1, 1,-1,-1,-1},
    { 1,-1, 1,-1, 1, 1, 1,-1},
    { 1,-1,-1, 1, 1,-1, 1, 1},
    { 1, 1,-1,-1, 1, 1,-1, 1}};

// ---------------- k1: setup (Ht, zero cnt/stats) + pack epack ----------------
__global__ __launch_bounds__(256) void setup_pack_kernel(const float* __restrict__ W,
                                                         __half* __restrict__ Ht,
                                                         int* __restrict__ cnt,
                                                         float* __restrict__ stats,
                                                         const int* __restrict__ arow,
                                                         const int* __restrict__ acol,
                                                         const float* __restrict__ aval,
                                                         uint2* __restrict__ epack) {
    const int i = blockIdx.x * 256 + threadIdx.x;
    if (i < D * D) {
        int ccol = i >> 7, k = i & 127;
        int ii = k >> 4, kw = k & 15, j = ccol >> 4, m = ccol & 15;
        Ht[i] = __float2half(OCT_S[j][ii] * W[kw * D + OCT_C[j][ii] * 16 + m]);
    }
    if (i < N_NODES) cnt[i] = 0;
    if (i < 2 * D) stats[i] = 0.0f;
    const int base = i * 4;
    if (base + 4 <= N_EDGES) {
        int4   r4 = *reinterpret_cast<const int4*>(arow + base);
        int4   c4 = *reinterpret_cast<const int4*>(acol + base);
        float4 v4 = *reinterpret_cast<const float4*>(aval + base);
        uint2 o[4];
        o[0] = make_uint2(((unsigned)c4.x & 0xFFFFu) | ((unsigned)__half_as_ushort(__float2half(v4.x)) << 16), (unsigned)r4.x);
        o[1] = make_uint2(((unsigned)c4.y & 0xFFFFu) | ((unsigned)__half_as_ushort(__float2half(v4.y)) << 16), (unsigned)r4.y);
        o[2] = make_uint2(((unsigned)c4.z & 0xFFFFu) | ((unsigned)__half_as_ushort(__float2half(v4.z)) << 16), (unsigned)r4.z);
        o[3] = make_uint2(((unsigned)c4.w & 0xFFFFu) | ((unsigned)__half_as_ushort(__float2half(v4.w)) << 16), (unsigned)r4.w);
        reinterpret_cast<uint4*>(epack + base)[0] = *reinterpret_cast<uint4*>(&o[0]);
        reinterpret_cast<uint4*>(epack + base)[1] = *reinterpret_cast<uint4*>(&o[2]);
    }
}

// ---------------- k2: wave-split fusion — waves 0-1 gemm, waves 2-7 scatter ----------------
// Both roles are co-resident on every CU from t=0, so the MFMA-bound gemm hides
// entirely under the latency-bound scatter. No __syncthreads anywhere.
__global__ __launch_bounds__(512) void gemm_scatter_kernel(const uint2* __restrict__ epack,
                                                           int* __restrict__ cnt,
                                                           unsigned* __restrict__ bucket,
                                                           const float* __restrict__ in,
                                                           const __half* __restrict__ Ht,
                                                           __half* __restrict__ support) {
    const int b = blockIdx.x;
    const int tid = threadIdx.x;
    if (tid >= 128) {
        // ---- scatter (waves 2..7), XCD-pinned, 4x unrolled for MLP ----
        const int g = b & 7;
        const int rank = b >> 3;                 // 0..255 within group
        const int r0 = g * RROWS, r1 = r0 + RROWS;
        const unsigned long long* ep = reinterpret_cast<const unsigned long long*>(epack);
        int i = rank * SC_THREADS + (tid - 128);
        for (; i + 3 * SC_STRIDE < N_EDGES; i += 4 * SC_STRIDE) {
            unsigned long long e0 = __builtin_nontemporal_load(ep + i);
            unsigned long long e1 = __builtin_nontemporal_load(ep + i + SC_STRIDE);
            unsigned long long e2 = __builtin_nontemporal_load(ep + i + 2 * SC_STRIDE);
            unsigned long long e3 = __builtin_nontemporal_load(ep + i + 3 * SC_STRIDE);
            int ra = (int)(e0 >> 32);
            if (ra >= r0 && ra < r1) {
                int slot = atomicAdd(&cnt[ra], 1);
                if (slot < CAP) bucket[(size_t)ra * CAP + slot] = (unsigned)e0;
            }
            int rb = (int)(e1 >> 32);
            if (rb >= r0 && rb < r1) {
                int slot = atomicAdd(&cnt[rb], 1);
                if (slot < CAP) bucket[(size_t)rb * CAP + slot] = (unsigned)e1;
            }
            int rc = (int)(e2 >> 32);
            if (rc >= r0 && rc < r1) {
                int slot = atomicAdd(&cnt[rc], 1);
                if (slot < CAP) bucket[(size_t)rc * CAP + slot] = (unsigned)e2;
            }
            int rd = (int)(e3 >> 32);
            if (rd >= r0 && rd < r1) {
                int slot = atomicAdd(&cnt[rd], 1);
                if (slot < CAP) bucket[(size_t)rd * CAP + slot] = (unsigned)e3;
            }
        }
        for (; i < N_EDGES; i += SC_STRIDE) {
            unsigned long long e = __builtin_nontemporal_load(ep + i);
            int r = (int)(e >> 32);
            if (r >= r0 && r < r1) {
                int slot = atomicAdd(&cnt[r], 1);
                if (slot < CAP) bucket[(size_t)r * CAP + slot] = (unsigned)e;
            }
        }
        return;
    }
    // ---- gemm (waves 0,1): tile = b*2 + wave ----
    const int wv = tid >> 6;
    const int tile = b * 2 + wv;
    if (tile >= N_TILES) return;
    const int lane = tid & 63;
    const int s = lane & 15;
    const int t = lane >> 4;

    half8 bb[8][4];
#pragma unroll
    for (int kk = 0; kk < 4; ++kk)
#pragma unroll
        for (int n = 0; n < 8; ++n)
            bb[n][kk] = *reinterpret_cast<const half8*>(Ht + (size_t)(16 * n + s) * D + kk * 32 + 8 * t);

    const float* ap = in + (size_t)(tile * 16 + s) * D;
    half8 a[4];
#pragma unroll
    for (int kk = 0; kk < 4; ++kk) {
        float4 f0 = *reinterpret_cast<const float4*>(ap + kk * 32 + 8 * t);
        float4 f1 = *reinterpret_cast<const float4*>(ap + kk * 32 + 8 * t + 4);
        a[kk][0] = (_Float16)f0.x; a[kk][1] = (_Float16)f0.y;
        a[kk][2] = (_Float16)f0.z; a[kk][3] = (_Float16)f0.w;
        a[kk][4] = (_Float16)f1.x; a[kk][5] = (_Float16)f1.y;
        a[kk][6] = (_Float16)f1.z; a[kk][7] = (_Float16)f1.w;
    }

    floatx4 acc[8];
#pragma unroll
    for (int n = 0; n < 8; ++n) acc[n] = (floatx4){0.f, 0.f, 0.f, 0.f};
#pragma unroll
    for (int kk = 0; kk < 4; ++kk)
#pragma unroll
        for (int n = 0; n < 8; ++n)
            acc[n] = __builtin_amdgcn_mfma_f32_16x16x32_f16(a[kk], bb[n][kk], acc[n], 0, 0, 0);

    __half* sp = support + (size_t)(tile * 16 + 4 * t) * D + s;
#pragma unroll
    for (int r = 0; r < 4; ++r)
#pragma unroll
        for (int n = 0; n < 8; ++n)
            sp[(size_t)r * D + 16 * n] = __float2half(acc[n][r]);
}

// ---------------- XCD-sliced bucket spmm, 2 rows/wave, pk_fma_f16 (R9 known-good) ----------------
__global__ __launch_bounds__(256) void spmm_kernel(const __half* __restrict__ support,
                                                   const int* __restrict__ cnt,
                                                   const unsigned* __restrict__ bucket,
                                                   __half* __restrict__ outh,
                                                   float* __restrict__ colsum,
                                                   float* __restrict__ colsq) {
    const int tid = threadIdx.x;
    const int lane = tid & 63;
    const int wv = tid >> 6;
    const int h = lane >> 4;          // edge group 0..3
    const int cl = lane & 15;         // column lane
    const int b = blockIdx.x;
    const int slice = (b & 7) >> 1;
    const int rank = ((b >> 3) << 1) | (b & 1);   // 0..511 within slice
    const int nrank = SPMM_BLOCKS >> 2;           // 512
    const int colbase = slice * SCOLS + cl * 2;

    __shared__ float lsum[SCOLS], lsq[SCOLS];
    if (tid < SCOLS) { lsum[tid] = 0.f; lsq[tid] = 0.f; }
    __syncthreads();

    float s0 = 0.f, s1 = 0.f, q0 = 0.f, q1 = 0.f;

    for (int row = rank * 8 + wv * 2; row < N_NODES; row += nrank * 8) {
        const int rowb = row + 1;
        int na = cnt[row]; na = na < CAP ? na : CAP;
        int nb = (rowb < N_NODES) ? cnt[rowb] : 0; nb = nb < CAP ? nb : CAP;
        const unsigned ewa = (lane < na) ? bucket[(size_t)row * CAP + lane] : 0u;
        const unsigned ewb = (lane < nb) ? bucket[(size_t)rowb * CAP + lane] : 0u;
        __half2 acca = __half2half2(__ushort_as_half((unsigned short)0));
        __half2 accb = acca;
        const int nmax = na > nb ? na : nb;
        const int n16 = (nmax + 15) & ~15;
        for (int e = 0; e < n16; e += 16) {
            unsigned ua[4], ub[4];
            __half2 ga[4], gb[4];
#pragma unroll
            for (int j = 0; j < 4; ++j) {
                int idx = e + j * 4 + h;
                ua[j] = __shfl(ewa, idx);       // idx>=n lanes broadcast 0 -> col0,val0
                ub[j] = __shfl(ewb, idx);
            }
#pragma unroll
            for (int j = 0; j < 4; ++j) {
                ga[j] = *reinterpret_cast<const __half2*>(support + (size_t)(ua[j] & 0xFFFFu) * D + colbase);
                gb[j] = *reinterpret_cast<const __half2*>(support + (size_t)(ub[j] & 0xFFFFu) * D + colbase);
            }
#pragma unroll
            for (int j = 0; j < 4; ++j) {
                unsigned va2 = __builtin_amdgcn_perm(ua[j], ua[j], 0x07060706u); // (val,val)
                unsigned vb2 = __builtin_amdgcn_perm(ub[j], ub[j], 0x07060706u);
                acca = __hfma2(*reinterpret_cast<__half2*>(&va2), ga[j], acca);
                accb = __hfma2(*reinterpret_cast<__half2*>(&vb2), gb[j], accb);
            }
        }
        // combine the 4 edge groups
#pragma unroll
        for (int off = 16; off <= 32; off <<= 1) {
            int ia = __shfl_xor(*reinterpret_cast<int*>(&acca), off);
            int ib = __shfl_xor(*reinterpret_cast<int*>(&accb), off);
            acca = __hadd2(acca, *reinterpret_cast<__half2*>(&ia));
            accb = __hadd2(accb, *reinterpret_cast<__half2*>(&ib));
        }
        if (h == 0) {
            float2 fa = __half22float2(acca);
            *reinterpret_cast<__half2*>(outh + (size_t)row * D + colbase) = acca;
            s0 += fa.x; s1 += fa.y; q0 += fa.x * fa.x; q1 += fa.y * fa.y;
            if (rowb < N_NODES) {
                float2 fb = __half22float2(accb);
                *reinterpret_cast<__half2*>(outh + (size_t)rowb * D + colbase) = accb;
                s0 += fb.x; s1 += fb.y; q0 += fb.x * fb.x; q1 += fb.y * fb.y;
            }
        }
    }

    if (h == 0) {
        atomicAdd(&lsum[cl * 2 + 0], s0); atomicAdd(&lsum[cl * 2 + 1], s1);
        atomicAdd(&lsq[cl * 2 + 0], q0);  atomicAdd(&lsq[cl * 2 + 1], q1);
    }
    __syncthreads();
    if (tid < SCOLS) {
        atomicAdd(&colsum[slice * SCOLS + tid], lsum[tid]);
        atomicAdd(&colsq[slice * SCOLS + tid], lsq[tid]);
    }
}

// ---------------- BN + tanh: read fp16 outh, write fp32 out ----------------
__global__ __launch_bounds__(256) void bn_tanh_kernel(const __half* __restrict__ outh,
                                                      float* __restrict__ out,
                                                      const float* __restrict__ colsum,
                                                      const float* __restrict__ colsq,
                                                      const float* __restrict__ gamma,
                                                      const float* __restrict__ beta) {
    __shared__ float scale[D], shift[D];
    const int tid = threadIdx.x;
    if (tid < D) {
        float mean = colsum[tid] * (1.0f / N_NODES);
        float var  = colsq[tid] * (1.0f / N_NODES) - mean * mean;
        float sc   = rsqrtf(var + BN_EPS) * gamma[tid];
        scale[tid] = sc;
        shift[tid] = beta[tid] - mean * sc;
    }
    __syncthreads();
    const int nq = N_NODES * D / 8;   // units of 8 halves
    for (int i = blockIdx.x * 256 + tid; i < nq; i += gridDim.x * 256) {
        uint4 v = reinterpret_cast<const uint4*>(outh)[i];
        const int c = (i & 15) * 8;
        float r[8];
        float2 f;
        f = __half22float2(*reinterpret_cast<__half2*>(&v.x)); r[0] = f.x; r[1] = f.y;
        f = __half22float2(*reinterpret_cast<__half2*>(&v.y)); r[2] = f.x; r[3] = f.y;
        f = __half22float2(*reinterpret_cast<__half2*>(&v.z)); r[4] = f.x; r[5] = f.y;
        f = __half22float2(*reinterpret_cast<__half2*>(&v.w)); r[6] = f.x; r[7] = f.y;
#pragma unroll
        for (int k = 0; k < 8; ++k) {
            float x = r[k] * scale[c + k] + shift[c + k];
            float e = __expf(2.0f * x);
            r[k] = 1.0f - 2.0f / (1.0f + e);
        }
        float4 o0 = make_float4(r[0], r[1], r[2], r[3]);
        float4 o1 = make_float4(r[4], r[5], r[6], r[7]);
        reinterpret_cast<float4*>(out)[i * 2 + 0] = o0;
        reinterpret_cast<float4*>(out)[i * 2 + 1] = o1;
    }
}

// ---------------- launch ----------------
extern "C" void kernel_launch(void* const* d_in, const int* in_sizes, int n_in,
                              void* d_out, int out_size, void* d_ws, size_t ws_size,
                              hipStream_t stream) {
    const float* input  = (const float*)d_in[0];
    const int*   arow   = (const int*)d_in[1];
    const int*   acol   = (const int*)d_in[2];
    const float* aval   = (const float*)d_in[3];
    const float* weight = (const float*)d_in[4];
    const float* gamma  = (const float*)d_in[5];
    const float* beta   = (const float*)d_in[6];
    float* out = (float*)d_out;

    __half*   support = (__half*)d_ws;                              // 12.8 MB
    unsigned* bucket  = (unsigned*)(support + (size_t)N_NODES * D); // 12.8 MB
    __half*   outh    = (__half*)(bucket + (size_t)N_NODES * CAP);  // 12.8 MB
    uint2*    epack   = (uint2*)outh;                               // aliases outh (consumed before spmm writes)
    int*      cnt     = (int*)(outh + (size_t)N_NODES * D);         // 200 KB
    float*    colsum  = (float*)(cnt + N_NODES);                    // 128 (+128 colsq)
    __half*   Ht      = (__half*)(colsum + 2 * D);                  // 32 KB

    setup_pack_kernel<<<782, 256, 0, stream>>>(weight, Ht, cnt, colsum,
                                               arow, acol, aval, epack);
    gemm_scatter_kernel<<<SPMM_BLOCKS, 512, 0, stream>>>(epack, cnt, bucket,
                                                         input, Ht, support);
    spmm_kernel<<<SPMM_BLOCKS, 256, 0, stream>>>(support, cnt, bucket, outh, colsum, colsum + D);
    bn_tanh_kernel<<<2048, 256, 0, stream>>>(outh, out, colsum, colsum + D, gamma, beta);
}